// Round 7
// baseline (659.618 us; speedup 1.0000x reference)
//
#include <hip/hip_runtime.h>
#include <math.h>

#define BS 512
#define NN 256
#define RB 16
#define OMEGA_F 1.5f

// ---------------------------------------------------------------------------
// Round-6 lesson: the backend budgets VGPRs to the LDS-limited occupancy
// (64 KB/512thr -> 2 blk/CU -> 4 waves/SIMD -> 128 VGPRs) and SPILLS the
// excess; amdgpu_waves_per_eu/launch_bounds hints don't override it. So:
// make peak pressure fit 128 by construction.
//
// Kernel 1 (sor_solve, 512 thr): two column panels of 128 -> 4 threads per
// column, g[4][16]=64 regs (was 128 -> ~35-reg spill). Thread (t2=tid&127,
// q=tid>>7) solves column c=p*128+t2 of G = (D+wL)^{-1}(-(wU+(w-1)D)) by
// blocked forward substitution; trailing GEMM reads A with wave-uniform
// GLOBAL addresses (s_load path, LDS pipe stays free), X from registers
// (compile-time indices only -- round-4 lesson). After each 16-row solve,
// xbuf holds complete G-rows; they are written straight to global in the
// ITERATE layout arr4[j4*256 + r] = {G[r][4j4..4j4+3]} (coalesced 256B
// chunks), so no separate transpose phase and no >128-reg live overlap.
// LDS padded to 56 KB to pin the 2-blk/CU / 128-VGPR operating point.
//
// Kernel 2 (sor_iterate, 1024 thr): thread (r=tid&255, qq=tid>>8) holds
// gq[16] float4 = quarter-row of G (64 regs), loaded once, coalesced.
// LDS sized 84 KB -> 1 blk/CU -> 4 waves/SIMD -> 128-VGPR budget, no spill.
// e <- G e with zero global traffic per iteration; per-batch early exit
// (deviation from the reference's global-done semantics <= xtol ~ 6e-8,
// far below the 0.3625 threshold -- validated rounds 1-6).
// ---------------------------------------------------------------------------

__global__ __launch_bounds__(512) void sor_solve(
    const float* __restrict__ A,
    float4* __restrict__ arr)              // BS * 64 * 256 float4 (128 MB)
{
    const int b   = blockIdx.x;
    const int tid = threadIdx.x;
    const int t2  = tid & 127;                           // column within panel
    const int q   = tid >> 7;                            // 0..3, wave-uniform
    const int qU  = __builtin_amdgcn_readfirstlane(q);
    const float* __restrict__ Ab   = A + (size_t)b * NN * NN;
    float4* __restrict__       arrB = arr + (size_t)b * (NN / 4) * NN;

    __shared__ __align__(16) char smem[57344];           // 56 KB -> 2 blk/CU
    float (*ldsA)[NN]      = (float (*)[NN])(smem);              // 16 KB A panel
    float (*bufs)[RB][128] = (float (*)[RB][128])(smem + 16384); // 24 KB partials
    float (*xbuf)[128]     = (float (*)[128])(smem + 40960);     // 8 KB solved rows

    for (int p = 0; p < 2; ++p) {                        // column panel
        const int c = p * 128 + t2;                      // this thread's G column
        float g[4][RB];                                  // X[j][c], kb = 4m+q

        for (int KB = 0; KB < NN / RB; ++KB) {
            const int r0 = KB * RB;
            __syncthreads();                             // prev readers done
            // stage A rows [r0, r0+16) x [0,256): 2 coalesced float4/thread
            #pragma unroll
            for (int i = 0; i < 2; ++i) {
                const int lin = tid + 512 * i;
                const int rr = lin >> 6, c4 = (lin & 63) << 2;
                *(float4*)&ldsA[rr][c4] = *(const float4*)&Ab[(size_t)(r0 + rr) * NN + c4];
            }
            __syncthreads();

            // trailing GEMM: acc[rr] = sum over owned j<r0 of A[r0+rr][j]*X[j][c]
            float acc[RB];
            #pragma unroll
            for (int rr = 0; rr < RB; ++rr) acc[rr] = 0.f;
            #pragma unroll
            for (int m = 0; m < 4; ++m) {
                const int kb = 4 * m + qU;
                if (kb < KB) {                           // wave-uniform branch
                    const int j0 = kb * RB;
                    #pragma unroll
                    for (int jw = 0; jw < 4; ++jw) {
                        const float g0 = g[m][4 * jw + 0];
                        const float g1 = g[m][4 * jw + 1];
                        const float g2 = g[m][4 * jw + 2];
                        const float g3 = g[m][4 * jw + 3];
                        #pragma unroll
                        for (int hc = 0; hc < 4; ++hc) {
                            float4 a_[4];                // wave-uniform -> s_load
                            #pragma unroll
                            for (int h = 0; h < 4; ++h)
                                a_[h] = *(const float4*)&Ab[(size_t)(r0 + 4 * hc + h) * NN + j0 + 4 * jw];
                            #pragma unroll
                            for (int h = 0; h < 4; ++h)
                                acc[4 * hc + h] += a_[h].x * g0 + a_[h].y * g1
                                                 + a_[h].z * g2 + a_[h].w * g3;
                        }
                    }
                }
            }
            // reduce 4 q-partials: q1..q3 publish, q0 sums
            if (q >= 1) {
                #pragma unroll
                for (int rr = 0; rr < RB; ++rr) bufs[q - 1][rr][t2] = acc[rr];
            }
            __syncthreads();
            // serial 16-row solve on q==0 threads (cols of this panel)
            if (q == 0) {
                float s_[RB];
                #pragma unroll
                for (int rr = 0; rr < RB; ++rr)
                    s_[rr] = acc[rr] + bufs[0][rr][t2] + bufs[1][rr][t2] + bufs[2][rr][t2];
                #pragma unroll
                for (int rr = 0; rr < RB; ++rr) {
                    const int r = r0 + rr;
                    const float a_rc = ldsA[rr][c];
                    const float brc  = (c > r) ? (-OMEGA_F) * a_rc
                                     : ((c == r) ? (1.0f - OMEGA_F) * a_rc : 0.0f);
                    const float diag = ldsA[rr][r];      // uniform broadcast
                    const float val  = (brc - OMEGA_F * s_[rr]) / diag;
                    xbuf[rr][t2] = val;
                    #pragma unroll
                    for (int rr2 = rr + 1; rr2 < RB; ++rr2)
                        s_[rr2] += ldsA[rr2][r] * val;   // right-looking update
                }
            }
            __syncthreads();
            // owner pulls solved rows into registers (compile-time indices)
            #pragma unroll
            for (int m = 0; m < 4; ++m) {
                if (KB == 4 * m + q) {
                    #pragma unroll
                    for (int rr = 0; rr < RB; ++rr) g[m][rr] = xbuf[rr][t2];
                }
            }
            // write the 16 finished (row, panel-col) G entries to global in
            // iterate layout: arr4[j4*256 + r] = {G[r][4j4..4j4+3]}
            {
                const int rr  = tid & 15;                // row within block
                const int j4l = tid >> 4;                // 0..31 panel j-quad
                const float4 v = *(const float4*)&xbuf[rr][4 * j4l];
                arrB[(size_t)(p * 32 + j4l) * NN + r0 + rr] = v;  // 256B chunks
            }
        }
    }
}

__global__ __launch_bounds__(1024) void sor_iterate(
    const float4* __restrict__ arr,
    const float* __restrict__ xs,
    const float* __restrict__ x0,
    const float* __restrict__ rtol,
    const int* __restrict__ maxiter_p,
    float* __restrict__ out)
{
    const int b   = blockIdx.x;
    const int tid = threadIdx.x;
    const int r   = tid & 255;                           // output row
    const int qq  = tid >> 8;                            // j-quarter, wave-uniform
    const int qqU = __builtin_amdgcn_readfirstlane(qq);
    const float4* __restrict__ arrB = arr + (size_t)b * (NN / 4) * NN;

    __shared__ __align__(16) char smem[86016];           // 84 KB -> 1 blk/CU
    float* e           = (float*)smem;                   // e[256]
    float (*pbuf)[NN]  = (float (*)[NN])(smem + 1024);   // 4x256 partials
    float* nrm         = (float*)(smem + 1024 + 4096);   // [0..3] err, [4..7] xs

    // one-time coalesced G load: gq[k] = {G[r][qq*64+4k .. +3]}
    float4 gq[16];
    #pragma unroll
    for (int k = 0; k < 16; ++k)
        gq[k] = arrB[(size_t)(qqU * 16 + k) * NN + r];

    const int mi = *maxiter_p;
    float* __restrict__ outb = out + (size_t)b * (mi + 1);

    // prologue: e0, err0 = ||xs-x0||, xtol = ||xs||*rtol
    if (tid < NN) {
        const float xsv = xs[b * NN + tid];
        const float ev  = xsv - x0[b * NN + tid];
        e[tid] = ev;
        float s1 = ev * ev, s2 = xsv * xsv;
        #pragma unroll
        for (int off = 32; off > 0; off >>= 1) {
            s1 += __shfl_down(s1, off);
            s2 += __shfl_down(s2, off);
        }
        if ((tid & 63) == 0) { nrm[tid >> 6] = s1; nrm[4 + (tid >> 6)] = s2; }
    }
    __syncthreads();
    const float err0 = sqrtf(nrm[0] + nrm[1] + nrm[2] + nrm[3]);
    const float xtol = sqrtf(nrm[4] + nrm[5] + nrm[6] + nrm[7]) * rtol[b];
    if (tid == 0) outb[0] = err0;

    float err = err0;
    int s = 1;
    for (; s <= mi; ++s) {
        if (!(err > xtol)) break;                        // block-uniform
        float a = 0.f;
        #pragma unroll
        for (int k = 0; k < 16; ++k) {
            const float4 e4 = *(const float4*)&e[qqU * 64 + 4 * k];  // broadcast
            a += gq[k].x * e4.x + gq[k].y * e4.y + gq[k].z * e4.z + gq[k].w * e4.w;
        }
        pbuf[qq][r] = a;
        __syncthreads();                                 // e reads + partials done
        if (tid < NN) {
            const float sum = pbuf[0][tid] + pbuf[1][tid] + pbuf[2][tid] + pbuf[3][tid];
            e[tid] = sum;                                // e <- G e
            float loc = sum * sum;
            #pragma unroll
            for (int off = 32; off > 0; off >>= 1) loc += __shfl_down(loc, off);
            if ((tid & 63) == 0) nrm[tid >> 6] = loc;
        }
        __syncthreads();
        err = sqrtf(nrm[0] + nrm[1] + nrm[2] + nrm[3]);
        if (tid == 0) outb[s] = err;
    }
    // zero-fill the unwritten tail
    for (int idx = s + tid; idx <= mi; idx += 1024) outb[idx] = 0.f;
}

extern "C" void kernel_launch(void* const* d_in, const int* in_sizes, int n_in,
                              void* d_out, int out_size, void* d_ws, size_t ws_size,
                              hipStream_t stream) {
    const float* A     = (const float*)d_in[0];
    // d_in[1] = b: unused (error iteration e_{k+1} = G e_k needs no affine term)
    const float* xs    = (const float*)d_in[2];
    const float* theta = (const float*)d_in[3];
    const float* rtol  = (const float*)d_in[4];
    const int*   mi    = (const int*)d_in[5];
    float* out = (float*)d_out;

    float4* arr = (float4*)d_ws;                         // 128 MB G in iterate layout

    sor_solve<<<dim3(BS), dim3(512), 0, stream>>>(A, arr);
    sor_iterate<<<dim3(BS), dim3(1024), 0, stream>>>(
        arr, xs, theta, rtol, mi, out);
}